// Round 16
// baseline (104.998 us; speedup 1.0000x reference)
//
#include <hip/hip_runtime.h>
#include <hip/hip_bf16.h>

#define N_NODES 50000
#define N_EDGES 800000
#define IN_DIM 128
#define OUT_DIM 64
#define REL_DIM 32
#define NEG_SLOPE 0.01f
#define NB 391            // coarse buckets: 128 dst nodes each (391*128 = 50048)
#define BWIN 2560         // fixed per-bucket window (Poisson(2048): max over 391 ~ 2200)
#define NBLK_A 782        // role-A blocks: ceil(50000/64)
#define K23_GRID 2346     // 3*NBLK_A; role A = blockIdx%3==0, else role B (1564 blocks)

// ================= kS: s1/s2 via u-vectors (s1[n] = (Wfc^T wa1).h[n]) + ccur zero ============
// Each block redundantly computes u1,u2 (64x128x2 FMA, Wfc L2-hot), stages 64 h-rows in LDS,
// then 4 threads/node quad-reduce the 128-dot. Decouples k3's s1/s2 dependency from the GEMM.
__global__ __launch_bounds__(256) void kS_s1s2(const float* __restrict__ h,
                                               const float* __restrict__ Wfc,
                                               const float* __restrict__ Wattn,
                                               float* __restrict__ s1,
                                               float* __restrict__ s2,
                                               unsigned* __restrict__ ccur) {
    __shared__ float u[2][128];
    __shared__ float hl[64][129];   // pad 129: write ~4-way, read 4-way (tiny traffic)
    const int t = threadIdx.x;
    const int blk = blockIdx.x;
    if (blk == 0) {
        for (int i = t; i < NB * 16; i += 256) ccur[i] = 0u;
    }
    {   // u compute: waves 0-1 -> u1, waves 2-3 -> u2
        int k = t & 127;
        int which = t >> 7;
        const float* wa = Wattn + (which ? 96 : 0);
        float acc = 0.f;
#pragma unroll 8
        for (int c = 0; c < 64; ++c)
            acc += wa[c] * Wfc[c * 128 + k];
        u[which][k] = acc;
    }
    const int n0 = blk * 64;
    const float4* h4 = (const float4*)h;
#pragma unroll
    for (int i = 0; i < 8; ++i) {
        int idx = t + 256 * i;           // 0..2047
        int n = idx >> 5, k4 = idx & 31;
        int gn = n0 + n; if (gn > N_NODES - 1) gn = N_NODES - 1;
        float4 v = h4[(size_t)gn * 32 + k4];
        hl[n][k4*4+0] = v.x; hl[n][k4*4+1] = v.y;
        hl[n][k4*4+2] = v.z; hl[n][k4*4+3] = v.w;
    }
    __syncthreads();
    const int n = t >> 2, cg = t & 3;    // 4 threads per node, 32 dims each
    float r1 = 0.f, r2 = 0.f;
#pragma unroll 8
    for (int i = 0; i < 32; ++i) {
        float hv = hl[n][cg * 32 + i];
        r1 += hv * u[0][cg * 32 + i];
        r2 += hv * u[1][cg * 32 + i];
    }
    r1 += __shfl_xor(r1, 1, 64); r1 += __shfl_xor(r1, 2, 64);
    r2 += __shfl_xor(r2, 1, 64); r2 += __shfl_xor(r2, 2, 64);
    int gn = n0 + n;
    if ((t & 3) == 0 && gn < N_NODES) { s1[gn] = r1; s2[gn] = r2; }
}

// ================= K23 fused: z-GEMM (role A) || p-stream + logit + binning (role B) =========
// Role A: z = h @ Wfc^T register-tiled, K-quarter LDS tiles (no s1/s2 epilogue).
// Role B: wave-contiguous p-stream dotp (shfl8 + in-wave transpose), then inline
//         ev = leakyrelu(s1[src]+dotp+s2[dst]) and LDS-staged binning into bucket windows
//         (merges old k2+k3: dotp round-trip and one dispatch eliminated).
__global__ __launch_bounds__(256) void k23_fused(const float* __restrict__ h,
                                                 const float* __restrict__ Wfc,
                                                 const float* __restrict__ Wattn,
                                                 const float* __restrict__ p,
                                                 const int* __restrict__ src,
                                                 const int* __restrict__ dst,
                                                 const float* __restrict__ s1,
                                                 const float* __restrict__ s2,
                                                 __hip_bfloat16* __restrict__ zb,
                                                 unsigned* __restrict__ ccur,
                                                 float2* __restrict__ pair) {
    __shared__ union SMem {
        struct { float Wl[32][68]; float hl[32][68]; } a;   // role A: 17.4 KB
        struct { unsigned hist[NB]; unsigned gb[NB]; unsigned lcur[NB]; } b;  // role B: 4.7 KB
    } sm;
    const int t = threadIdx.x;
    const int b = blockIdx.x;

    if (b % 3 == 0) {
        // ---------------- role A: GEMM (4 K-quarters of 32) ----------------
        const int blk = b / 3;
        const int cg = t & 15, ng = t >> 4;
        const int c0 = cg * 4;
        const int n0 = blk * 64;
        float acc[4][4] = {};
        const float4* W4 = (const float4*)Wfc;   // [64][32] float4
        const float4* h4 = (const float4*)h;     // [N][32] float4

#pragma unroll
        for (int Q = 0; Q < 4; ++Q) {
            __syncthreads();   // protect LDS from previous quarter's readers
#pragma unroll
            for (int i = 0; i < 2; ++i) {
                int idx = t + 256 * i;               // 0..511
                int c = idx & 63, k4l = idx >> 6;
                float4 v = W4[c * 32 + Q * 8 + k4l];
                sm.a.Wl[4*k4l+0][c] = v.x; sm.a.Wl[4*k4l+1][c] = v.y;
                sm.a.Wl[4*k4l+2][c] = v.z; sm.a.Wl[4*k4l+3][c] = v.w;
            }
#pragma unroll
            for (int i = 0; i < 2; ++i) {
                int idx = t + 256 * i;
                int n = idx & 63, k4l = idx >> 6;
                int gn = n0 + n; if (gn > N_NODES - 1) gn = N_NODES - 1;
                float4 v = h4[(size_t)gn * 32 + Q * 8 + k4l];
                sm.a.hl[4*k4l+0][n] = v.x; sm.a.hl[4*k4l+1][n] = v.y;
                sm.a.hl[4*k4l+2][n] = v.z; sm.a.hl[4*k4l+3][n] = v.w;
            }
            __syncthreads();
#pragma unroll 8
            for (int k = 0; k < 32; ++k) {
                float4 wv = *(const float4*)&sm.a.Wl[k][c0];
                float4 hv = *(const float4*)&sm.a.hl[k][ng * 4];
                float wvf[4] = {wv.x, wv.y, wv.z, wv.w};
                float hvf[4] = {hv.x, hv.y, hv.z, hv.w};
#pragma unroll
                for (int i = 0; i < 4; ++i)
#pragma unroll
                    for (int j = 0; j < 4; ++j) acc[i][j] += hvf[i] * wvf[j];
            }
        }

#pragma unroll
        for (int i = 0; i < 4; ++i) {
            int gn = n0 + ng * 4 + i;
            if (gn < N_NODES) {
                __hip_bfloat16 b0 = __float2bfloat16(acc[i][0]);
                __hip_bfloat16 b1 = __float2bfloat16(acc[i][1]);
                __hip_bfloat16 b2 = __float2bfloat16(acc[i][2]);
                __hip_bfloat16 b3 = __float2bfloat16(acc[i][3]);
                ushort4 st;
                st.x = *(unsigned short*)&b0; st.y = *(unsigned short*)&b1;
                st.z = *(unsigned short*)&b2; st.w = *(unsigned short*)&b3;
                ((ushort4*)zb)[(size_t)gn * 16 + cg] = st;
            }
        }
    } else {
        // ---------------- role B: p-stream + logit + binning ----------------
        const int kb = b - b / 3 - 1;          // 0..1563
        unsigned* hist = sm.b.hist;
        unsigned* gb   = sm.b.gb;
        unsigned* lcur = sm.b.lcur;
        for (int i = t; i < NB; i += 256) hist[i] = 0;
        __syncthreads();

        const int lane = t & 63;
        const int q = lane & 7;
        const float w0 = Wattn[64 + q * 4 + 0];
        const float w1 = Wattn[64 + q * 4 + 1];
        const float w2 = Wattn[64 + q * 4 + 2];
        const float w3 = Wattn[64 + q * 4 + 3];
        const float4* p4 = (const float4*)p;

        float evr[2]; unsigned auxr[2]; int br[2];
#pragma unroll
        for (int c = 0; c < 2; ++c) {
            br[c] = -1;
            const int grp = (kb * 4 + (t >> 6)) * 2 + c;   // 64-edge group
            if (grp < 12500) {
                const int base4 = grp * 512;   // contiguous 8KB per group
                float4 v[8];
#pragma unroll
                for (int j = 0; j < 8; ++j) v[j] = p4[base4 + j * 64 + lane];
                float d[8];
#pragma unroll
                for (int j = 0; j < 8; ++j)
                    d[j] = v[j].x * w0 + v[j].y * w1 + v[j].z * w2 + v[j].w * w3;
#pragma unroll
                for (int off = 1; off < 8; off <<= 1)
#pragma unroll
                    for (int j = 0; j < 8; ++j) d[j] += __shfl_xor(d[j], off, 64);
                // in-wave 8x8 transpose: lane l takes d[l>>3] from lane (l&7)*8
                float val = 0.f;
#pragma unroll
                for (int j = 0; j < 8; ++j) {
                    float tmp = __shfl(d[j], (lane & 7) * 8, 64);
                    if ((lane >> 3) == j) val = tmp;
                }
                const int e = grp * 64 + lane;
                int s = src[e], dd = dst[e];
                float a = s1[s] + val + s2[dd];
                float ev = a > 0.f ? a : NEG_SLOPE * a;
                evr[c] = ev;
                auxr[c] = (unsigned)s | ((unsigned)(dd & 127) << 16);
                int bb = dd >> 7;
                br[c] = bb;
                atomicAdd(&hist[bb], 1u);
            }
        }
        __syncthreads();
        for (int i = t; i < NB; i += 256) {
            lcur[i] = 0;
            gb[i] = hist[i] ? (i * BWIN + atomicAdd(&ccur[i * 16], hist[i])) : 0u;
        }
        __syncthreads();
#pragma unroll
        for (int c = 0; c < 2; ++c) {
            if (br[c] >= 0) {
                unsigned pos = atomicAdd(&lcur[br[c]], 1u);
                pair[gb[br[c]] + pos] = make_float2(evr[c], __uint_as_float(auxr[c]));
            }
        }
    }
}

// ================= K3b: within-bucket sort to per-node order + per-node beg/end ===============
__global__ __launch_bounds__(256) void k3b_sort(const unsigned* __restrict__ ccur,
                                                const float2* __restrict__ pair,
                                                float2* __restrict__ pair2,
                                                unsigned* __restrict__ beg_g,
                                                unsigned* __restrict__ end_g) {
    __shared__ float2 items[BWIN];          // 20.5KB
    __shared__ unsigned hist[128], loffs[128], lcur[128], sd[128];
    const int t = threadIdx.x;
    const int b = blockIdx.x;
    const int base = b * BWIN;
    int cnt = (int)ccur[b * 16];
    if (cnt > BWIN) cnt = BWIN;             // safety clamp (deterministic input: never hit)
    if (t < 128) { hist[t] = 0; lcur[t] = 0; }
    __syncthreads();
    for (int i = t; i < cnt; i += 256) {
        float2 it = pair[base + i];
        items[i] = it;
        atomicAdd(&hist[__float_as_uint(it.y) >> 16], 1u);
    }
    __syncthreads();
    unsigned v = (t < 128) ? hist[t] : 0u;
    if (t < 128) sd[t] = v;
    __syncthreads();
#pragma unroll
    for (int off = 1; off < 128; off <<= 1) {
        unsigned tmp = (t >= off && t < 128) ? sd[t - off] : 0u;
        __syncthreads();
        if (t < 128) sd[t] += tmp;
        __syncthreads();
    }
    if (t < 128) {
        unsigned ex = sd[t] - v;
        loffs[t] = ex;
        beg_g[b * 128 + t] = base + ex;
        end_g[b * 128 + t] = base + ex + v;
    }
    __syncthreads();
    for (int i = t; i < cnt; i += 256) {
        float2 it = items[i];
        unsigned dl = __float_as_uint(it.y) >> 16;
        unsigned pos = atomicAdd(&lcur[dl], 1u);
        pair2[base + loffs[dl] + pos] = it;
    }
}

// ================= K4: 4-nodes-per-wave segment aggregate =================
__global__ __launch_bounds__(256) void k4_agg(const unsigned* __restrict__ beg_g,
                                              const unsigned* __restrict__ end_g,
                                              const float2* __restrict__ pair2,
                                              const __hip_bfloat16* __restrict__ zb,
                                              float* __restrict__ out) {
    const int t = threadIdx.x;
    const int lane = t & 63;
    const int sub = lane >> 4;               // node sub-index in wave
    const int lc = lane & 15;                // column group (cols lc*4 .. lc*4+3)
    const int wid = (blockIdx.x * 256 + t) >> 6;   // 0..12499
    const int n = wid * 4 + sub;             // 0..49999 (exact cover)
    const int lo = beg_g[n], hi = end_g[n];
    const ushort* zs = (const ushort*)zb;
    float a0 = 0.f, a1 = 0.f, a2 = 0.f, a3 = 0.f, den = 0.f;
    int i = lo;
    for (; i + 3 < hi; i += 4) {
        float2 pr[4];
#pragma unroll
        for (int j = 0; j < 4; ++j) pr[j] = pair2[i + j];
        ushort4 zv[4];
#pragma unroll
        for (int j = 0; j < 4; ++j) {
            int s = __float_as_uint(pr[j].y) & 0xFFFF;
            zv[j] = *(const ushort4*)&zs[s * OUT_DIM + lc * 4];
        }
#pragma unroll
        for (int j = 0; j < 4; ++j) {
            float e = __expf(pr[j].x);
            a0 += e * __uint_as_float((unsigned)zv[j].x << 16);
            a1 += e * __uint_as_float((unsigned)zv[j].y << 16);
            a2 += e * __uint_as_float((unsigned)zv[j].z << 16);
            a3 += e * __uint_as_float((unsigned)zv[j].w << 16);
            den += e;
        }
    }
    for (; i < hi; ++i) {
        float2 p0 = pair2[i];
        int s = __float_as_uint(p0.y) & 0xFFFF;
        ushort4 zv = *(const ushort4*)&zs[s * OUT_DIM + lc * 4];
        float e = __expf(p0.x);
        a0 += e * __uint_as_float((unsigned)zv.x << 16);
        a1 += e * __uint_as_float((unsigned)zv.y << 16);
        a2 += e * __uint_as_float((unsigned)zv.z << 16);
        a3 += e * __uint_as_float((unsigned)zv.w << 16);
        den += e;
    }
    float4 st;
    if (hi > lo) {
        float inv = 1.f / den;
        st.x = a0 * inv; st.y = a1 * inv; st.z = a2 * inv; st.w = a3 * inv;
    } else {
        st.x = st.y = st.z = st.w = 0.f;
    }
    ((float4*)out)[(size_t)n * 16 + lc] = st;
}

extern "C" void kernel_launch(void* const* d_in, const int* in_sizes, int n_in,
                              void* d_out, int out_size, void* d_ws, size_t ws_size,
                              hipStream_t stream) {
    const float* h     = (const float*)d_in[0];
    const float* p     = (const float*)d_in[1];
    const int*   src   = (const int*)d_in[2];
    const int*   dst   = (const int*)d_in[3];
    const float* Wfc   = (const float*)d_in[4];
    const float* Wattn = (const float*)d_in[5];
    float* out = (float*)d_out;

    // workspace layout (float words)
    float* ws = (float*)d_ws;
    __hip_bfloat16* zb = (__hip_bfloat16*)ws;        // 3,200,000 bf16 = 1,600,000 floats
    float*    s1     = ws + 1600000;                 // 50,000
    float*    s2     = ws + 1650000;                 // 50,000
    unsigned* ccur   = (unsigned*)(ws + 1700000);    // 6,272 (391*16, 64B-strided)
    unsigned* beg_g  = (unsigned*)(ws + 1706272);    // 50,048
    unsigned* end_g  = (unsigned*)(ws + 1756320);    // 50,048
    float2*   pair   = (float2*)(ws + 1806368);      // NB*BWIN = 1,000,960 float2
    float2*   pair2  = (float2*)(ws + 3808288);      // 1,000,960 float2
    // total: 5,810,208 floats = 23.2 MB

    kS_s1s2<<<NBLK_A, 256, 0, stream>>>(h, Wfc, Wattn, s1, s2, ccur);
    k23_fused<<<K23_GRID, 256, 0, stream>>>(h, Wfc, Wattn, p, src, dst, s1, s2, zb, ccur, pair);
    k3b_sort<<<NB, 256, 0, stream>>>(ccur, pair, pair2, beg_g, end_g);
    k4_agg<<<3125, 256, 0, stream>>>(beg_g, end_g, pair2, zb, out);
}

// Round 17
// 93.504 us; speedup vs baseline: 1.1229x; 1.1229x over previous
//
#include <hip/hip_runtime.h>
#include <hip/hip_bf16.h>

#define N_NODES 50000
#define N_EDGES 800000
#define IN_DIM 128
#define OUT_DIM 64
#define REL_DIM 32
#define NEG_SLOPE 0.01f
#define NB 391            // coarse buckets: 128 dst nodes each (391*128 = 50048)
#define K3_TILE 2048
#define K3_BLOCKS ((N_EDGES + K3_TILE - 1) / K3_TILE)   // 391
#define BWIN 2560         // fixed per-bucket window (Poisson(2048): max over 391 ~ 2200)

typedef __attribute__((ext_vector_type(8))) short bf16x8;
typedef __attribute__((ext_vector_type(4))) float f32x4;

__device__ __forceinline__ short f2bf(float f) {
    unsigned u = __float_as_uint(f);
    u += 0x7FFF + ((u >> 16) & 1);   // RNE bf16 (inputs are normal floats)
    return (short)(u >> 16);
}

// ================= K1: z = h @ Wfc^T via MFMA 16x16x32 bf16; s1/s2 fused; no LDS ============
// One wave per 16-node tile (3125 tiles exactly). A = Wfc-tile [16 cols x 32 k],
// B = h-tile [32 k x 16 nodes]  =>  D[c_off][node]: lane holds node (lane&15), cols
// ct*16 + (lane>>4)*4 + i  -> consecutive cols => ushort4 z-stores; s1/s2 via 2 shfl_xor.
// k-permutation inside fragments cancels between A and B (dot over k), so only the
// lane&15 = (A-row / B-col) mapping matters; C/D mapping is the m89-verified one.
__global__ __launch_bounds__(256) void k1_mfma(const float* __restrict__ h,
                                               const float* __restrict__ Wfc,
                                               const float* __restrict__ Wattn,
                                               __hip_bfloat16* __restrict__ zb,
                                               float* __restrict__ s1,
                                               float* __restrict__ s2,
                                               unsigned* __restrict__ ccur) {
    const int t = threadIdx.x;
    if (blockIdx.x == 0) {
        for (int i = t; i < NB * 16; i += 256) ccur[i] = 0u;
    }
    const int nt = blockIdx.x * 4 + (t >> 6);   // node tile, 0..3124
    if (nt >= 3125) return;
    const int lane = t & 63;
    const int r = lane & 15;      // A row (col-offset) / B col (node-offset)
    const int g = lane >> 4;      // k-group 0..3
    const int n0 = nt * 16;

    const float4* hrow = (const float4*)(h + (size_t)(n0 + r) * IN_DIM);
    f32x4 acc[4] = {{0.f,0.f,0.f,0.f},{0.f,0.f,0.f,0.f},{0.f,0.f,0.f,0.f},{0.f,0.f,0.f,0.f}};

#pragma unroll
    for (int kq = 0; kq < 4; ++kq) {
        float4 h0 = hrow[kq * 8 + g * 2];
        float4 h1 = hrow[kq * 8 + g * 2 + 1];
        bf16x8 hb;
        hb[0] = f2bf(h0.x); hb[1] = f2bf(h0.y); hb[2] = f2bf(h0.z); hb[3] = f2bf(h0.w);
        hb[4] = f2bf(h1.x); hb[5] = f2bf(h1.y); hb[6] = f2bf(h1.z); hb[7] = f2bf(h1.w);
#pragma unroll
        for (int ct = 0; ct < 4; ++ct) {
            const float4* wrow = (const float4*)(Wfc + (size_t)(ct * 16 + r) * IN_DIM);
            float4 w0 = wrow[kq * 8 + g * 2];
            float4 w1 = wrow[kq * 8 + g * 2 + 1];
            bf16x8 wb;
            wb[0] = f2bf(w0.x); wb[1] = f2bf(w0.y); wb[2] = f2bf(w0.z); wb[3] = f2bf(w0.w);
            wb[4] = f2bf(w1.x); wb[5] = f2bf(w1.y); wb[6] = f2bf(w1.z); wb[7] = f2bf(w1.w);
            acc[ct] = __builtin_amdgcn_mfma_f32_16x16x32_bf16(wb, hb, acc[ct], 0, 0, 0);
        }
    }

    // epilogue: lane holds z[n0+r][ct*16 + g*4 + i]
    float r1 = 0.f, r2 = 0.f;
#pragma unroll
    for (int ct = 0; ct < 4; ++ct) {
#pragma unroll
        for (int i = 0; i < 4; ++i) {
            int c = ct * 16 + g * 4 + i;
            r1 += acc[ct][i] * Wattn[c];
            r2 += acc[ct][i] * Wattn[96 + c];
        }
        ushort4 st;
        st.x = (ushort)f2bf(acc[ct][0]); st.y = (ushort)f2bf(acc[ct][1]);
        st.z = (ushort)f2bf(acc[ct][2]); st.w = (ushort)f2bf(acc[ct][3]);
        ((ushort4*)zb)[(size_t)(n0 + r) * 16 + ct * 4 + g] = st;
    }
    r1 += __shfl_xor(r1, 16, 64); r1 += __shfl_xor(r1, 32, 64);
    r2 += __shfl_xor(r2, 16, 64); r2 += __shfl_xor(r2, 32, 64);
    if (g == 0) { s1[n0 + r] = r1; s2[n0 + r] = r2; }
}

// ================= K2: wave-contiguous p-stream -> dotp =================
// Wave owns contiguous 8KB (64 edges): 8x 1KB wave-loads, shfl8 reduce + in-wave
// 8x8 transpose -> one coalesced 256B store per group. Natural edge order out.
__global__ __launch_bounds__(256) void k2_dotp(const float* __restrict__ p,
                                               const float* __restrict__ Wattn,
                                               float* __restrict__ dotp) {
    const int t = threadIdx.x;
    const int lane = t & 63;
    const int wv = blockIdx.x * 4 + (t >> 6);   // 0..6255
    const int q = lane & 7;
    const float w0 = Wattn[64 + q * 4 + 0];
    const float w1 = Wattn[64 + q * 4 + 1];
    const float w2 = Wattn[64 + q * 4 + 2];
    const float w3 = Wattn[64 + q * 4 + 3];
    const float4* p4 = (const float4*)p;
#pragma unroll
    for (int c = 0; c < 2; ++c) {
        const int grp = wv * 2 + c;             // 64-edge group, 12500 used
        if (grp < 12500) {
            const int base4 = grp * 512;        // contiguous 8KB
            float4 v[8];
#pragma unroll
            for (int j = 0; j < 8; ++j) v[j] = p4[base4 + j * 64 + lane];
            float d[8];
#pragma unroll
            for (int j = 0; j < 8; ++j)
                d[j] = v[j].x * w0 + v[j].y * w1 + v[j].z * w2 + v[j].w * w3;
#pragma unroll
            for (int off = 1; off < 8; off <<= 1)
#pragma unroll
                for (int j = 0; j < 8; ++j) d[j] += __shfl_xor(d[j], off, 64);
            float val = 0.f;
#pragma unroll
            for (int j = 0; j < 8; ++j) {
                float tmp = __shfl(d[j], (lane & 7) * 8, 64);
                if ((lane >> 3) == j) val = tmp;
            }
            dotp[grp * 64 + lane] = val;
        }
    }
}

// ================= K3: logit assembly + leaky-relu + binning into fixed bucket windows ========
// pair item: (ev, aux) with aux = src | (d_local << 16)
__global__ __launch_bounds__(256) void k3_fused(const float* __restrict__ dotp,
                                                const int* __restrict__ src,
                                                const int* __restrict__ dst,
                                                const float* __restrict__ s1,
                                                const float* __restrict__ s2,
                                                unsigned* __restrict__ ccur,
                                                float2* __restrict__ pair) {
    __shared__ unsigned hist[NB];
    __shared__ unsigned gb[NB];
    __shared__ unsigned lcur[NB];
    const int t = threadIdx.x;
    for (int i = t; i < NB; i += 256) hist[i] = 0;
    __syncthreads();

    const int base = blockIdx.x * K3_TILE;
    float evr[8];
    unsigned auxr[8];
    short br[8];
#pragma unroll
    for (int i = 0; i < 8; ++i) {
        int e = base + i * 256 + t;
        if (e < N_EDGES) {
            int s = src[e], d = dst[e];
            float a = s1[s] + dotp[e] + s2[d];
            evr[i] = a > 0.f ? a : NEG_SLOPE * a;
            auxr[i] = (unsigned)s | ((unsigned)(d & 127) << 16);
            int bb = d >> 7;
            br[i] = (short)bb;
            atomicAdd(&hist[bb], 1u);
        } else br[i] = -1;
    }
    __syncthreads();
    for (int i = t; i < NB; i += 256) {
        lcur[i] = 0;
        gb[i] = hist[i] ? (i * BWIN + atomicAdd(&ccur[i * 16], hist[i])) : 0u;
    }
    __syncthreads();
#pragma unroll
    for (int i = 0; i < 8; ++i) {
        if (br[i] >= 0) {
            int bb = br[i];
            unsigned pos = atomicAdd(&lcur[bb], 1u);
            pair[gb[bb] + pos] = make_float2(evr[i], __uint_as_float(auxr[i]));
        }
    }
}

// ================= K3b: within-bucket sort to per-node order + per-node beg/end ===============
__global__ __launch_bounds__(256) void k3b_sort(const unsigned* __restrict__ ccur,
                                                const float2* __restrict__ pair,
                                                float2* __restrict__ pair2,
                                                unsigned* __restrict__ beg_g,
                                                unsigned* __restrict__ end_g) {
    __shared__ float2 items[BWIN];          // 20.5KB
    __shared__ unsigned hist[128], loffs[128], lcur[128], sd[128];
    const int t = threadIdx.x;
    const int b = blockIdx.x;
    const int base = b * BWIN;
    int cnt = (int)ccur[b * 16];
    if (cnt > BWIN) cnt = BWIN;             // safety clamp (deterministic input: never hit)
    if (t < 128) { hist[t] = 0; lcur[t] = 0; }
    __syncthreads();
    for (int i = t; i < cnt; i += 256) {
        float2 it = pair[base + i];
        items[i] = it;
        atomicAdd(&hist[__float_as_uint(it.y) >> 16], 1u);
    }
    __syncthreads();
    unsigned v = (t < 128) ? hist[t] : 0u;
    if (t < 128) sd[t] = v;
    __syncthreads();
#pragma unroll
    for (int off = 1; off < 128; off <<= 1) {
        unsigned tmp = (t >= off && t < 128) ? sd[t - off] : 0u;
        __syncthreads();
        if (t < 128) sd[t] += tmp;
        __syncthreads();
    }
    if (t < 128) {
        unsigned ex = sd[t] - v;
        loffs[t] = ex;
        beg_g[b * 128 + t] = base + ex;
        end_g[b * 128 + t] = base + ex + v;
    }
    __syncthreads();
    for (int i = t; i < cnt; i += 256) {
        float2 it = items[i];
        unsigned dl = __float_as_uint(it.y) >> 16;
        unsigned pos = atomicAdd(&lcur[dl], 1u);
        pair2[base + loffs[dl] + pos] = it;
    }
}

// ================= K4: 4-nodes-per-wave segment aggregate =================
__global__ __launch_bounds__(256) void k4_agg(const unsigned* __restrict__ beg_g,
                                              const unsigned* __restrict__ end_g,
                                              const float2* __restrict__ pair2,
                                              const __hip_bfloat16* __restrict__ zb,
                                              float* __restrict__ out) {
    const int t = threadIdx.x;
    const int lane = t & 63;
    const int sub = lane >> 4;               // node sub-index in wave
    const int lc = lane & 15;                // column group (cols lc*4 .. lc*4+3)
    const int wid = (blockIdx.x * 256 + t) >> 6;   // 0..12499
    const int n = wid * 4 + sub;             // 0..49999 (exact cover)
    const int lo = beg_g[n], hi = end_g[n];
    const ushort* zs = (const ushort*)zb;
    float a0 = 0.f, a1 = 0.f, a2 = 0.f, a3 = 0.f, den = 0.f;
    int i = lo;
    for (; i + 3 < hi; i += 4) {
        float2 pr[4];
#pragma unroll
        for (int j = 0; j < 4; ++j) pr[j] = pair2[i + j];
        ushort4 zv[4];
#pragma unroll
        for (int j = 0; j < 4; ++j) {
            int s = __float_as_uint(pr[j].y) & 0xFFFF;
            zv[j] = *(const ushort4*)&zs[s * OUT_DIM + lc * 4];
        }
#pragma unroll
        for (int j = 0; j < 4; ++j) {
            float e = __expf(pr[j].x);
            a0 += e * __uint_as_float((unsigned)zv[j].x << 16);
            a1 += e * __uint_as_float((unsigned)zv[j].y << 16);
            a2 += e * __uint_as_float((unsigned)zv[j].z << 16);
            a3 += e * __uint_as_float((unsigned)zv[j].w << 16);
            den += e;
        }
    }
    for (; i < hi; ++i) {
        float2 p0 = pair2[i];
        int s = __float_as_uint(p0.y) & 0xFFFF;
        ushort4 zv = *(const ushort4*)&zs[s * OUT_DIM + lc * 4];
        float e = __expf(p0.x);
        a0 += e * __uint_as_float((unsigned)zv.x << 16);
        a1 += e * __uint_as_float((unsigned)zv.y << 16);
        a2 += e * __uint_as_float((unsigned)zv.z << 16);
        a3 += e * __uint_as_float((unsigned)zv.w << 16);
        den += e;
    }
    float4 st;
    if (hi > lo) {
        float inv = 1.f / den;
        st.x = a0 * inv; st.y = a1 * inv; st.z = a2 * inv; st.w = a3 * inv;
    } else {
        st.x = st.y = st.z = st.w = 0.f;
    }
    ((float4*)out)[(size_t)n * 16 + lc] = st;
}

extern "C" void kernel_launch(void* const* d_in, const int* in_sizes, int n_in,
                              void* d_out, int out_size, void* d_ws, size_t ws_size,
                              hipStream_t stream) {
    const float* h     = (const float*)d_in[0];
    const float* p     = (const float*)d_in[1];
    const int*   src   = (const int*)d_in[2];
    const int*   dst   = (const int*)d_in[3];
    const float* Wfc   = (const float*)d_in[4];
    const float* Wattn = (const float*)d_in[5];
    float* out = (float*)d_out;

    // workspace layout (float words)
    float* ws = (float*)d_ws;
    __hip_bfloat16* zb = (__hip_bfloat16*)ws;        // 3,200,000 bf16 = 1,600,000 floats
    float*    s1     = ws + 1600000;                 // 50,000
    float*    s2     = ws + 1650000;                 // 50,000
    float*    dotp   = ws + 1700000;                 // 800,000
    unsigned* ccur   = (unsigned*)(ws + 2500000);    // 6,272 (391*16, 64B-strided)
    unsigned* beg_g  = (unsigned*)(ws + 2506272);    // 50,048
    unsigned* end_g  = (unsigned*)(ws + 2556320);    // 50,048
    float2*   pair   = (float2*)(ws + 2606368);      // NB*BWIN = 1,000,960 float2 (16B-aligned)
    float2*   pair2  = (float2*)(ws + 4608288);      // 1,000,960 float2 (16B-aligned)
    // total: 6,610,208 floats = 26.4 MB

    k1_mfma<<<782, 256, 0, stream>>>(h, Wfc, Wattn, zb, s1, s2, ccur);
    k2_dotp<<<1564, 256, 0, stream>>>(p, Wattn, dotp);
    k3_fused<<<K3_BLOCKS, 256, 0, stream>>>(dotp, src, dst, s1, s2, ccur, pair);
    k3b_sort<<<NB, 256, 0, stream>>>(ccur, pair, pair2, beg_g, end_g);
    k4_agg<<<3125, 256, 0, stream>>>(beg_g, end_g, pair2, zb, out);
}

// Round 18
// 87.558 us; speedup vs baseline: 1.1992x; 1.0679x over previous
//
#include <hip/hip_runtime.h>
#include <hip/hip_bf16.h>

#define N_NODES 50000
#define N_EDGES 800000
#define IN_DIM 128
#define OUT_DIM 64
#define REL_DIM 32
#define NEG_SLOPE 0.01f
#define NB 391            // coarse buckets: 128 dst nodes each (391*128 = 50048)
#define K3_TILE 2048
#define K3_BLOCKS ((N_EDGES + K3_TILE - 1) / K3_TILE)   // 391
#define BWIN 2560         // fixed per-bucket window (Poisson(2048): max over 391 ~ 2200)
#define K12_GRID 25000    // 25000*256 threads = 6,400,000 = exactly one float4 of p each

typedef __attribute__((ext_vector_type(8))) short bf16x8;
typedef __attribute__((ext_vector_type(4))) float f32x4;

__device__ __forceinline__ short f2bf(float f) {
    unsigned u = __float_as_uint(f);
    u += 0x7FFF + ((u >> 16) & 1);   // RNE bf16 (inputs are normal floats)
    return (short)(u >> 16);
}

// ================= K12: MFMA GEMM (first 782 blocks) + max-TLP p-stream (all blocks) =========
// Stream: ONE float4 per thread (6.4M threads) -> load, 4 FMA, 3 shfl_xor, store per 8 lanes.
// No loops, no LDS, no batch-sync: concurrency comes from ~100K waves (vs 6256 before).
// GEMM: r17's verified MFMA path (one wave per 16-node tile, scattered loads OK at this TLP);
// s1/s2 fused in epilogue; ccur zeroed by block 782. 25K lightweight blocks self-balance.
__global__ __launch_bounds__(256) void k12_fused(const float* __restrict__ h,
                                                 const float* __restrict__ Wfc,
                                                 const float* __restrict__ Wattn,
                                                 const float* __restrict__ p,
                                                 __hip_bfloat16* __restrict__ zb,
                                                 float* __restrict__ s1,
                                                 float* __restrict__ s2,
                                                 float* __restrict__ dotp,
                                                 unsigned* __restrict__ ccur) {
    const int t = threadIdx.x;
    const int b = blockIdx.x;

    if (b == 782) {
        for (int i = t; i < NB * 16; i += 256) ccur[i] = 0u;
    }

    // ---------------- GEMM phase (blocks 0..781; wave-tiles of 16 nodes) ----------------
    if (b < 782) {
        const int nt = b * 4 + (t >> 6);         // 0..3127, guard to 3125
        if (nt < 3125) {
            const int lane = t & 63;
            const int r = lane & 15;             // A row (col-offset) / B col (node-offset)
            const int g = lane >> 4;             // k-group 0..3
            const int n0 = nt * 16;

            const float4* hrow = (const float4*)(h + (size_t)(n0 + r) * IN_DIM);
            f32x4 acc[4] = {{0.f,0.f,0.f,0.f},{0.f,0.f,0.f,0.f},
                            {0.f,0.f,0.f,0.f},{0.f,0.f,0.f,0.f}};

#pragma unroll
            for (int kq = 0; kq < 4; ++kq) {
                float4 h0 = hrow[kq * 8 + g * 2];
                float4 h1 = hrow[kq * 8 + g * 2 + 1];
                bf16x8 hb;
                hb[0] = f2bf(h0.x); hb[1] = f2bf(h0.y); hb[2] = f2bf(h0.z); hb[3] = f2bf(h0.w);
                hb[4] = f2bf(h1.x); hb[5] = f2bf(h1.y); hb[6] = f2bf(h1.z); hb[7] = f2bf(h1.w);
#pragma unroll
                for (int ct = 0; ct < 4; ++ct) {
                    const float4* wrow = (const float4*)(Wfc + (size_t)(ct * 16 + r) * IN_DIM);
                    float4 w0 = wrow[kq * 8 + g * 2];
                    float4 w1 = wrow[kq * 8 + g * 2 + 1];
                    bf16x8 wb;
                    wb[0] = f2bf(w0.x); wb[1] = f2bf(w0.y); wb[2] = f2bf(w0.z); wb[3] = f2bf(w0.w);
                    wb[4] = f2bf(w1.x); wb[5] = f2bf(w1.y); wb[6] = f2bf(w1.z); wb[7] = f2bf(w1.w);
                    acc[ct] = __builtin_amdgcn_mfma_f32_16x16x32_bf16(wb, hb, acc[ct], 0, 0, 0);
                }
            }

            // epilogue: lane holds z[n0+r][ct*16 + g*4 + i]
            float r1 = 0.f, r2 = 0.f;
#pragma unroll
            for (int ct = 0; ct < 4; ++ct) {
#pragma unroll
                for (int i = 0; i < 4; ++i) {
                    int c = ct * 16 + g * 4 + i;
                    r1 += acc[ct][i] * Wattn[c];
                    r2 += acc[ct][i] * Wattn[96 + c];
                }
                ushort4 st;
                st.x = (ushort)f2bf(acc[ct][0]); st.y = (ushort)f2bf(acc[ct][1]);
                st.z = (ushort)f2bf(acc[ct][2]); st.w = (ushort)f2bf(acc[ct][3]);
                ((ushort4*)zb)[(size_t)(n0 + r) * 16 + ct * 4 + g] = st;
            }
            r1 += __shfl_xor(r1, 16, 64); r1 += __shfl_xor(r1, 32, 64);
            r2 += __shfl_xor(r2, 16, 64); r2 += __shfl_xor(r2, 32, 64);
            if (g == 0) { s1[n0 + r] = r1; s2[n0 + r] = r2; }
        }
    }

    // ---------------- stream phase (all 25000 blocks; one float4 each) ----------------
    {
        const int idx = b * 256 + t;             // 0..6,399,999 float4s of p (exact)
        const int q = t & 7;                     // quarter-row within edge (256 ≡ 0 mod 8)
        const float w0 = Wattn[64 + q * 4 + 0];
        const float w1 = Wattn[64 + q * 4 + 1];
        const float w2 = Wattn[64 + q * 4 + 2];
        const float w3 = Wattn[64 + q * 4 + 3];
        float4 v = ((const float4*)p)[idx];
        float d = v.x * w0 + v.y * w1 + v.z * w2 + v.w * w3;
        d += __shfl_xor(d, 1, 64);
        d += __shfl_xor(d, 2, 64);
        d += __shfl_xor(d, 4, 64);
        if (q == 0) dotp[idx >> 3] = d;          // 8 consecutive words per wave (32B seg)
    }
}

// ================= K3: logit assembly + leaky-relu + binning into fixed bucket windows ========
// pair item: (ev, aux) with aux = src | (d_local << 16)
__global__ __launch_bounds__(256) void k3_fused(const float* __restrict__ dotp,
                                                const int* __restrict__ src,
                                                const int* __restrict__ dst,
                                                const float* __restrict__ s1,
                                                const float* __restrict__ s2,
                                                unsigned* __restrict__ ccur,
                                                float2* __restrict__ pair) {
    __shared__ unsigned hist[NB];
    __shared__ unsigned gb[NB];
    __shared__ unsigned lcur[NB];
    const int t = threadIdx.x;
    for (int i = t; i < NB; i += 256) hist[i] = 0;
    __syncthreads();

    const int base = blockIdx.x * K3_TILE;
    float evr[8];
    unsigned auxr[8];
    short br[8];
#pragma unroll
    for (int i = 0; i < 8; ++i) {
        int e = base + i * 256 + t;
        if (e < N_EDGES) {
            int s = src[e], d = dst[e];
            float a = s1[s] + dotp[e] + s2[d];
            evr[i] = a > 0.f ? a : NEG_SLOPE * a;
            auxr[i] = (unsigned)s | ((unsigned)(d & 127) << 16);
            int bb = d >> 7;
            br[i] = (short)bb;
            atomicAdd(&hist[bb], 1u);
        } else br[i] = -1;
    }
    __syncthreads();
    for (int i = t; i < NB; i += 256) {
        lcur[i] = 0;
        gb[i] = hist[i] ? (i * BWIN + atomicAdd(&ccur[i * 16], hist[i])) : 0u;
    }
    __syncthreads();
#pragma unroll
    for (int i = 0; i < 8; ++i) {
        if (br[i] >= 0) {
            int bb = br[i];
            unsigned pos = atomicAdd(&lcur[bb], 1u);
            pair[gb[bb] + pos] = make_float2(evr[i], __uint_as_float(auxr[i]));
        }
    }
}

// ================= K3b: within-bucket sort to per-node order + per-node beg/end ===============
__global__ __launch_bounds__(256) void k3b_sort(const unsigned* __restrict__ ccur,
                                                const float2* __restrict__ pair,
                                                float2* __restrict__ pair2,
                                                unsigned* __restrict__ beg_g,
                                                unsigned* __restrict__ end_g) {
    __shared__ float2 items[BWIN];          // 20.5KB
    __shared__ unsigned hist[128], loffs[128], lcur[128], sd[128];
    const int t = threadIdx.x;
    const int b = blockIdx.x;
    const int base = b * BWIN;
    int cnt = (int)ccur[b * 16];
    if (cnt > BWIN) cnt = BWIN;             // safety clamp (deterministic input: never hit)
    if (t < 128) { hist[t] = 0; lcur[t] = 0; }
    __syncthreads();
    for (int i = t; i < cnt; i += 256) {
        float2 it = pair[base + i];
        items[i] = it;
        atomicAdd(&hist[__float_as_uint(it.y) >> 16], 1u);
    }
    __syncthreads();
    unsigned v = (t < 128) ? hist[t] : 0u;
    if (t < 128) sd[t] = v;
    __syncthreads();
#pragma unroll
    for (int off = 1; off < 128; off <<= 1) {
        unsigned tmp = (t >= off && t < 128) ? sd[t - off] : 0u;
        __syncthreads();
        if (t < 128) sd[t] += tmp;
        __syncthreads();
    }
    if (t < 128) {
        unsigned ex = sd[t] - v;
        loffs[t] = ex;
        beg_g[b * 128 + t] = base + ex;
        end_g[b * 128 + t] = base + ex + v;
    }
    __syncthreads();
    for (int i = t; i < cnt; i += 256) {
        float2 it = items[i];
        unsigned dl = __float_as_uint(it.y) >> 16;
        unsigned pos = atomicAdd(&lcur[dl], 1u);
        pair2[base + loffs[dl] + pos] = it;
    }
}

// ================= K4: 4-nodes-per-wave segment aggregate =================
__global__ __launch_bounds__(256) void k4_agg(const unsigned* __restrict__ beg_g,
                                              const unsigned* __restrict__ end_g,
                                              const float2* __restrict__ pair2,
                                              const __hip_bfloat16* __restrict__ zb,
                                              float* __restrict__ out) {
    const int t = threadIdx.x;
    const int lane = t & 63;
    const int sub = lane >> 4;               // node sub-index in wave
    const int lc = lane & 15;                // column group (cols lc*4 .. lc*4+3)
    const int wid = (blockIdx.x * 256 + t) >> 6;   // 0..12499
    const int n = wid * 4 + sub;             // 0..49999 (exact cover)
    const int lo = beg_g[n], hi = end_g[n];
    const ushort* zs = (const ushort*)zb;
    float a0 = 0.f, a1 = 0.f, a2 = 0.f, a3 = 0.f, den = 0.f;
    int i = lo;
    for (; i + 3 < hi; i += 4) {
        float2 pr[4];
#pragma unroll
        for (int j = 0; j < 4; ++j) pr[j] = pair2[i + j];
        ushort4 zv[4];
#pragma unroll
        for (int j = 0; j < 4; ++j) {
            int s = __float_as_uint(pr[j].y) & 0xFFFF;
            zv[j] = *(const ushort4*)&zs[s * OUT_DIM + lc * 4];
        }
#pragma unroll
        for (int j = 0; j < 4; ++j) {
            float e = __expf(pr[j].x);
            a0 += e * __uint_as_float((unsigned)zv[j].x << 16);
            a1 += e * __uint_as_float((unsigned)zv[j].y << 16);
            a2 += e * __uint_as_float((unsigned)zv[j].z << 16);
            a3 += e * __uint_as_float((unsigned)zv[j].w << 16);
            den += e;
        }
    }
    for (; i < hi; ++i) {
        float2 p0 = pair2[i];
        int s = __float_as_uint(p0.y) & 0xFFFF;
        ushort4 zv = *(const ushort4*)&zs[s * OUT_DIM + lc * 4];
        float e = __expf(p0.x);
        a0 += e * __uint_as_float((unsigned)zv.x << 16);
        a1 += e * __uint_as_float((unsigned)zv.y << 16);
        a2 += e * __uint_as_float((unsigned)zv.z << 16);
        a3 += e * __uint_as_float((unsigned)zv.w << 16);
        den += e;
    }
    float4 st;
    if (hi > lo) {
        float inv = 1.f / den;
        st.x = a0 * inv; st.y = a1 * inv; st.z = a2 * inv; st.w = a3 * inv;
    } else {
        st.x = st.y = st.z = st.w = 0.f;
    }
    ((float4*)out)[(size_t)n * 16 + lc] = st;
}

extern "C" void kernel_launch(void* const* d_in, const int* in_sizes, int n_in,
                              void* d_out, int out_size, void* d_ws, size_t ws_size,
                              hipStream_t stream) {
    const float* h     = (const float*)d_in[0];
    const float* p     = (const float*)d_in[1];
    const int*   src   = (const int*)d_in[2];
    const int*   dst   = (const int*)d_in[3];
    const float* Wfc   = (const float*)d_in[4];
    const float* Wattn = (const float*)d_in[5];
    float* out = (float*)d_out;

    // workspace layout (float words)
    float* ws = (float*)d_ws;
    __hip_bfloat16* zb = (__hip_bfloat16*)ws;        // 3,200,000 bf16 = 1,600,000 floats
    float*    s1     = ws + 1600000;                 // 50,000
    float*    s2     = ws + 1650000;                 // 50,000
    float*    dotp   = ws + 1700000;                 // 800,000
    unsigned* ccur   = (unsigned*)(ws + 2500000);    // 6,272 (391*16, 64B-strided)
    unsigned* beg_g  = (unsigned*)(ws + 2506272);    // 50,048
    unsigned* end_g  = (unsigned*)(ws + 2556320);    // 50,048
    float2*   pair   = (float2*)(ws + 2606368);      // NB*BWIN = 1,000,960 float2 (16B-aligned)
    float2*   pair2  = (float2*)(ws + 4608288);      // 1,000,960 float2 (16B-aligned)
    // total: 6,610,208 floats = 26.4 MB

    k12_fused<<<K12_GRID, 256, 0, stream>>>(h, Wfc, Wattn, p, zb, s1, s2, dotp, ccur);
    k3_fused<<<K3_BLOCKS, 256, 0, stream>>>(dotp, src, dst, s1, s2, ccur, pair);
    k3b_sort<<<NB, 256, 0, stream>>>(ccur, pair, pair2, beg_g, end_g);
    k4_agg<<<3125, 256, 0, stream>>>(beg_g, end_g, pair2, zb, out);
}